// Round 2
// baseline (2380.542 us; speedup 1.0000x reference)
//
#include <hip/hip_runtime.h>

// UniRNN: T=512,B=256,X=H1=H2=256, fp32 in/out.
// Split-precision (bf16 hi+lo) MFMA pipeline:
//   K1: x1 = A @ W_ih1^T + b_ih1        (A split, W split, fp32 out -> d_out)
//   K2: layer-1 scan, state split, W_hh1 split; h1 stream bf16 -> d_ws
//   K3: u  = h1 @ W_ih2^T + b_ih2+b_hh2 (A=h1 bf16, W split, fp32 -> d_out)
//   K4: layer-2 scan in place over u -> final output
// d_ws requirement: T*B*H*2 = 67,108,864 bytes.
//
// R2: scans are LDS-read-bound (each wave reads the FULL hi+lo state; rocprof
// R1: 44% MFMA / ~2700 of 3456 cyc/step in LDS at 8 waves).
// -> 4 waves/WG x 64 cols/wave: per-CU LDS state reads halve (128KB->64KB/step).
//    W fragments 256 VGPR/wave, __launch_bounds__(256,1). Math identical to R1.

#define TT 512
#define BB 256
#define HH 256
#define LSTR 280   // LDS row stride (bf16 elems); l15 stride = 140 dwords == 12 mod 32 -> 2-way (free)

typedef short bf16x8 __attribute__((ext_vector_type(8)));
typedef float f32x4  __attribute__((ext_vector_type(4)));

__device__ inline unsigned short f2bf(float f) {
    unsigned int u = __float_as_uint(f);
    u = u + 0x7fffu + ((u >> 16) & 1u);          // RNE
    return (unsigned short)(u >> 16);
}
__device__ inline float bf2f(unsigned short h) {
    return __uint_as_float(((unsigned int)h) << 16);
}
__device__ inline float tanh_fast(float x) {
    float e = __expf(2.0f * x);
    return 1.0f - 2.0f * __builtin_amdgcn_rcpf(e + 1.0f);
}
// LDS-visibility-only barrier: waits DS ops, does NOT drain vmcnt.
__device__ inline void lds_barrier() {
    asm volatile("s_waitcnt lgkmcnt(0)\n\ts_barrier" ::: "memory");
}
// 8 consecutive fp32 -> hi/lo bf16x8 fragments (split precision)
__device__ inline void pack_wfrag2(const float* __restrict__ wrow, bf16x8& hi, bf16x8& lo) {
    const float4* p = (const float4*)wrow;
    float4 v0 = p[0], v1 = p[1];
    float w[8] = {v0.x, v0.y, v0.z, v0.w, v1.x, v1.y, v1.z, v1.w};
#pragma unroll
    for (int i = 0; i < 8; ++i) {
        unsigned short h = f2bf(w[i]);
        hi[i] = (short)h;
        lo[i] = (short)f2bf(w[i] - bf2f(h));
    }
}
__device__ inline f32x4 mfma16(bf16x8 a, bf16x8 b, f32x4 c) {
    return __builtin_amdgcn_mfma_f32_16x16x32_bf16(a, b, c, 0, 0, 0);
}

// ---------------------------------------------------------------------------
// Projection GEMM (unchanged from R1): C[m,n] = sum_k A[m,k]*W[n,k] + bias(n).
// M = T*B = 131072, N = K = 256. Block 512 thr (8 waves), wave owns 32 cols.
// ---------------------------------------------------------------------------
template<bool IN_BF16, bool SPLIT_A>
__global__ __launch_bounds__(512, 2)
void proj_kernel(const void* __restrict__ Ain, const float* __restrict__ W,
                 const float* __restrict__ bias_a, const float* __restrict__ bias_b,
                 float* __restrict__ Cout)
{
    __shared__ unsigned short lds_hi[64 * LSTR];
    __shared__ unsigned short lds_lo[SPLIT_A ? 64 * LSTR : 1];
    const int tid  = threadIdx.x;
    const int lane = tid & 63, wv = tid >> 6;
    const int quad = lane >> 4, l15 = lane & 15;
    const int n0   = wv * 32;

    bf16x8 wh[2][8], wl[2][8];
    float  biasv[2];
#pragma unroll
    for (int nt = 0; nt < 2; ++nt) {
        int n = n0 + nt * 16 + l15;
        biasv[nt] = bias_a[n] + (bias_b ? bias_b[n] : 0.0f);
#pragma unroll
        for (int kc = 0; kc < 8; ++kc)
            pack_wfrag2(W + (size_t)n * HH + kc * 32 + quad * 8, wh[nt][kc], wl[nt][kc]);
    }

    for (int it = 0; it < 4; ++it) {
        const int m0 = (blockIdx.x * 4 + it) * 64;
        if (IN_BF16) {
            const unsigned short* A = (const unsigned short*)Ain;
#pragma unroll
            for (int j = 0; j < 4; ++j) {
                int c = tid + j * 512;            // 2048 chunks of 8 bf16
                int row = c >> 5, col8 = c & 31;
                uint4 v = *(const uint4*)(A + (size_t)(m0 + row) * HH + col8 * 8);
                *(uint4*)&lds_hi[row * LSTR + col8 * 8] = v;
            }
        } else {
            const float* A = (const float*)Ain;
#pragma unroll
            for (int j = 0; j < 8; ++j) {
                int c = tid + j * 512;            // 4096 chunks of 4 fp32
                int row = c >> 6, col4 = c & 63;
                float4 v = *(const float4*)(A + (size_t)(m0 + row) * HH + col4 * 4);
                unsigned short h0 = f2bf(v.x), h1 = f2bf(v.y), h2 = f2bf(v.z), h3 = f2bf(v.w);
                unsigned int p0 = (unsigned int)h0 | ((unsigned int)h1 << 16);
                unsigned int p1 = (unsigned int)h2 | ((unsigned int)h3 << 16);
                *(uint2*)&lds_hi[row * LSTR + col4 * 4] = make_uint2(p0, p1);
                if (SPLIT_A) {
                    unsigned int q0 = (unsigned int)f2bf(v.x - bf2f(h0)) |
                                      ((unsigned int)f2bf(v.y - bf2f(h1)) << 16);
                    unsigned int q1 = (unsigned int)f2bf(v.z - bf2f(h2)) |
                                      ((unsigned int)f2bf(v.w - bf2f(h3)) << 16);
                    *(uint2*)&lds_lo[row * LSTR + col4 * 4] = make_uint2(q0, q1);
                }
            }
        }
        __syncthreads();

        f32x4 acc[4][2];
#pragma unroll
        for (int mt = 0; mt < 4; ++mt)
#pragma unroll
            for (int nt = 0; nt < 2; ++nt)
                acc[mt][nt] = (f32x4){0.f, 0.f, 0.f, 0.f};

#pragma unroll
        for (int kc = 0; kc < 8; ++kc) {
            bf16x8 ah[4], al[4];
#pragma unroll
            for (int mt = 0; mt < 4; ++mt) {
                ah[mt] = *(const bf16x8*)&lds_hi[(mt * 16 + l15) * LSTR + kc * 32 + quad * 8];
                if (SPLIT_A)
                    al[mt] = *(const bf16x8*)&lds_lo[(mt * 16 + l15) * LSTR + kc * 32 + quad * 8];
            }
#pragma unroll
            for (int mt = 0; mt < 4; ++mt)
#pragma unroll
                for (int nt = 0; nt < 2; ++nt) {
                    acc[mt][nt] = mfma16(ah[mt], wh[nt][kc], acc[mt][nt]);
                    if (SPLIT_A)
                        acc[mt][nt] = mfma16(al[mt], wh[nt][kc], acc[mt][nt]);
                    acc[mt][nt] = mfma16(ah[mt], wl[nt][kc], acc[mt][nt]);
                }
        }

#pragma unroll
        for (int mt = 0; mt < 4; ++mt)
#pragma unroll
            for (int nt = 0; nt < 2; ++nt)
#pragma unroll
                for (int r = 0; r < 4; ++r) {
                    int row = m0 + mt * 16 + quad * 4 + r;
                    int col = n0 + nt * 16 + l15;
                    Cout[(size_t)row * HH + col] = acc[mt][nt][r] + biasv[nt];
                }
        __syncthreads();
    }
}

// ---------------------------------------------------------------------------
// Layer-1 scan: 16 WGs x 256 thr (4 waves). WG owns batch rows [m0,m0+16),
// wave owns 64 cols (4 nt fragments). State split hi+lo bf16 in LDS, W_hh1
// split in 256 VGPRs/wave. 3 MFMA passes/step: hi@Whi + lo@Whi + hi@Wlo.
// Per-CU LDS reads: 4 waves x 16KB = 64KB/step (was 128KB at 8 waves).
// ---------------------------------------------------------------------------
__global__ __launch_bounds__(256, 1)
void scan1_kernel(const float* __restrict__ x1,             // [T,B,H] fp32
                  const float* __restrict__ Whh1,
                  const float* __restrict__ bhh1,
                  const float* __restrict__ h0,             // [B,H] fp32
                  unsigned short* __restrict__ h1g,         // [T,B,H] bf16 out
                  float* __restrict__ h1f)                  // [B,H] fp32 final
{
    __shared__ unsigned short hs_hi[2][16 * LSTR];
    __shared__ unsigned short hs_lo[2][16 * LSTR];
    const int tid  = threadIdx.x;
    const int lane = tid & 63, wv = tid >> 6;    // wv 0..3
    const int quad = lane >> 4, l15 = lane & 15;
    const int m0   = blockIdx.x * 16;
    const int n0   = wv * 64;

    bf16x8 wh[4][8], wl[4][8];
    float  biasv[4];
#pragma unroll
    for (int nt = 0; nt < 4; ++nt) {
        int n = n0 + nt * 16 + l15;
        biasv[nt] = bhh1[n];
#pragma unroll
        for (int kc = 0; kc < 8; ++kc)
            pack_wfrag2(Whh1 + (size_t)n * HH + kc * 32 + quad * 8, wh[nt][kc], wl[nt][kc]);
    }
#pragma unroll
    for (int j = 0; j < 16; ++j) {
        int idx = tid + j * 256;
        int row = idx >> 8, col = idx & 255;
        float v = h0[(size_t)(m0 + row) * HH + col];
        unsigned short h = f2bf(v);
        hs_hi[0][row * LSTR + col] = h;
        hs_lo[0][row * LSTR + col] = f2bf(v - bf2f(h));
    }
    __syncthreads();

    const int colb = n0 + l15;
    const int rowb = quad * 4;

    // prefetch x(t=0)
    float xc[4][4];
#pragma unroll
    for (int nt = 0; nt < 4; ++nt)
#pragma unroll
        for (int r = 0; r < 4; ++r)
            xc[nt][r] = x1[(size_t)(m0 + rowb + r) * HH + colb + nt * 16];

    for (int t = 0; t < TT; ++t) {
        const int cur = t & 1, nxt = (t + 1) & 1;
        const size_t base = ((size_t)t * BB + m0) * HH;
        const int tn = (t + 1 < TT) ? (t + 1) : t;          // clamp (values unused on last iter)
        const size_t basen = ((size_t)tn * BB + m0) * HH;

        // prefetch x(t+1): consumed one full step later
        float xn[4][4];
#pragma unroll
        for (int nt = 0; nt < 4; ++nt)
#pragma unroll
            for (int r = 0; r < 4; ++r)
                xn[nt][r] = x1[basen + (size_t)(rowb + r) * HH + colb + nt * 16];

        f32x4 accA[4], accB[4];
#pragma unroll
        for (int nt = 0; nt < 4; ++nt) {
            accA[nt] = (f32x4){0.f,0.f,0.f,0.f};
            accB[nt] = (f32x4){0.f,0.f,0.f,0.f};
        }
#pragma unroll
        for (int kc = 0; kc < 4; ++kc) {
            const int kd = kc + 4;
            bf16x8 ahA = *(const bf16x8*)&hs_hi[cur][l15 * LSTR + kc * 32 + quad * 8];
            bf16x8 alA = *(const bf16x8*)&hs_lo[cur][l15 * LSTR + kc * 32 + quad * 8];
            bf16x8 ahB = *(const bf16x8*)&hs_hi[cur][l15 * LSTR + kd * 32 + quad * 8];
            bf16x8 alB = *(const bf16x8*)&hs_lo[cur][l15 * LSTR + kd * 32 + quad * 8];
#pragma unroll
            for (int nt = 0; nt < 4; ++nt) {
                accA[nt] = mfma16(ahA, wh[nt][kc], accA[nt]);
                accA[nt] = mfma16(alA, wh[nt][kc], accA[nt]);
                accA[nt] = mfma16(ahA, wl[nt][kc], accA[nt]);
                accB[nt] = mfma16(ahB, wh[nt][kd], accB[nt]);
                accB[nt] = mfma16(alB, wh[nt][kd], accB[nt]);
                accB[nt] = mfma16(ahB, wl[nt][kd], accB[nt]);
            }
        }

#pragma unroll
        for (int nt = 0; nt < 4; ++nt) {
            f32x4 acc = accA[nt] + accB[nt];
#pragma unroll
            for (int r = 0; r < 4; ++r) {
                float pre = acc[r] + xc[nt][r] + biasv[nt];
                float h   = tanh_fast(pre);
                unsigned short hb = f2bf(h);
                int row = rowb + r, col = colb + nt * 16;
                hs_hi[nxt][row * LSTR + col] = hb;
                hs_lo[nxt][row * LSTR + col] = f2bf(h - bf2f(hb));
                h1g[base + (size_t)row * HH + col] = hb;
                if (t == TT - 1) h1f[(size_t)(m0 + row) * HH + col] = h;
            }
        }
        lds_barrier();
#pragma unroll
        for (int nt = 0; nt < 4; ++nt)
#pragma unroll
            for (int r = 0; r < 4; ++r)
                xc[nt][r] = xn[nt][r];
    }
}

// ---------------------------------------------------------------------------
// Layer-2 scan: same 4-wave structure; u fp32 in/out in place (biases folded).
// ---------------------------------------------------------------------------
__global__ __launch_bounds__(256, 1)
void scan2_kernel(float* __restrict__ u,                    // [T,B,H] fp32, in/out
                  const float* __restrict__ Whh2,
                  const float* __restrict__ h0,             // [B,H] fp32
                  float* __restrict__ h2f)                  // [B,H] fp32 final
{
    __shared__ unsigned short hs_hi[2][16 * LSTR];
    __shared__ unsigned short hs_lo[2][16 * LSTR];
    const int tid  = threadIdx.x;
    const int lane = tid & 63, wv = tid >> 6;
    const int quad = lane >> 4, l15 = lane & 15;
    const int m0   = blockIdx.x * 16;
    const int n0   = wv * 64;

    bf16x8 wh[4][8], wl[4][8];
#pragma unroll
    for (int nt = 0; nt < 4; ++nt) {
        int n = n0 + nt * 16 + l15;
#pragma unroll
        for (int kc = 0; kc < 8; ++kc)
            pack_wfrag2(Whh2 + (size_t)n * HH + kc * 32 + quad * 8, wh[nt][kc], wl[nt][kc]);
    }
#pragma unroll
    for (int j = 0; j < 16; ++j) {
        int idx = tid + j * 256;
        int row = idx >> 8, col = idx & 255;
        float v = h0[(size_t)(m0 + row) * HH + col];
        unsigned short h = f2bf(v);
        hs_hi[0][row * LSTR + col] = h;
        hs_lo[0][row * LSTR + col] = f2bf(v - bf2f(h));
    }
    __syncthreads();

    const int colb = n0 + l15;
    const int rowb = quad * 4;

    // prefetch u(t=0)
    float uc[4][4];
#pragma unroll
    for (int nt = 0; nt < 4; ++nt)
#pragma unroll
        for (int r = 0; r < 4; ++r)
            uc[nt][r] = u[(size_t)(m0 + rowb + r) * HH + colb + nt * 16];

    for (int t = 0; t < TT; ++t) {
        const int cur = t & 1, nxt = (t + 1) & 1;
        const size_t base = ((size_t)t * BB + m0) * HH;
        const int tn = (t + 1 < TT) ? (t + 1) : t;
        const size_t basen = ((size_t)tn * BB + m0) * HH;

        // prefetch u(t+1); on last iter reads u(t) BEFORE this step's in-place
        // write (program order per lane) -> stale values, discarded. Safe.
        float un[4][4];
#pragma unroll
        for (int nt = 0; nt < 4; ++nt)
#pragma unroll
            for (int r = 0; r < 4; ++r)
                un[nt][r] = u[basen + (size_t)(rowb + r) * HH + colb + nt * 16];

        f32x4 accA[4], accB[4];
#pragma unroll
        for (int nt = 0; nt < 4; ++nt) {
            accA[nt] = (f32x4){0.f,0.f,0.f,0.f};
            accB[nt] = (f32x4){0.f,0.f,0.f,0.f};
        }
#pragma unroll
        for (int kc = 0; kc < 4; ++kc) {
            const int kd = kc + 4;
            bf16x8 ahA = *(const bf16x8*)&hs_hi[cur][l15 * LSTR + kc * 32 + quad * 8];
            bf16x8 alA = *(const bf16x8*)&hs_lo[cur][l15 * LSTR + kc * 32 + quad * 8];
            bf16x8 ahB = *(const bf16x8*)&hs_hi[cur][l15 * LSTR + kd * 32 + quad * 8];
            bf16x8 alB = *(const bf16x8*)&hs_lo[cur][l15 * LSTR + kd * 32 + quad * 8];
#pragma unroll
            for (int nt = 0; nt < 4; ++nt) {
                accA[nt] = mfma16(ahA, wh[nt][kc], accA[nt]);
                accA[nt] = mfma16(alA, wh[nt][kc], accA[nt]);
                accA[nt] = mfma16(ahA, wl[nt][kc], accA[nt]);
                accB[nt] = mfma16(ahB, wh[nt][kd], accB[nt]);
                accB[nt] = mfma16(alB, wh[nt][kd], accB[nt]);
                accB[nt] = mfma16(ahB, wl[nt][kd], accB[nt]);
            }
        }

#pragma unroll
        for (int nt = 0; nt < 4; ++nt) {
            f32x4 acc = accA[nt] + accB[nt];
#pragma unroll
            for (int r = 0; r < 4; ++r) {
                float pre = acc[r] + uc[nt][r];
                float h   = tanh_fast(pre);
                unsigned short hb = f2bf(h);
                int row = rowb + r, col = colb + nt * 16;
                hs_hi[nxt][row * LSTR + col] = hb;
                hs_lo[nxt][row * LSTR + col] = f2bf(h - bf2f(hb));
                u[base + (size_t)row * HH + col] = h;       // final output
                if (t == TT - 1) h2f[(size_t)(m0 + row) * HH + col] = h;
            }
        }
        lds_barrier();
#pragma unroll
        for (int nt = 0; nt < 4; ++nt)
#pragma unroll
            for (int r = 0; r < 4; ++r)
                uc[nt][r] = un[nt][r];
    }
}

extern "C" void kernel_launch(void* const* d_in, const int* in_sizes, int n_in,
                              void* d_out, int out_size, void* d_ws, size_t ws_size,
                              hipStream_t stream)
{
    const float* A     = (const float*)d_in[0];   // [T,B,X]
    const float* is1   = (const float*)d_in[1];   // [B,H1]
    const float* is2   = (const float*)d_in[2];   // [B,H2]
    const float* W_ih1 = (const float*)d_in[3];
    const float* W_hh1 = (const float*)d_in[4];
    const float* b_ih1 = (const float*)d_in[5];
    const float* b_hh1 = (const float*)d_in[6];
    const float* W_ih2 = (const float*)d_in[7];
    const float* W_hh2 = (const float*)d_in[8];
    const float* b_ih2 = (const float*)d_in[9];
    const float* b_hh2 = (const float*)d_in[10];

    float* out = (float*)d_out;
    const size_t OUT0 = (size_t)TT * BB * HH;          // 33554432
    float* x1  = out;                                  // fp32 scratch in out region
    unsigned short* h1g = (unsigned short*)d_ws;       // bf16 h1 stream, 67 MB
    float* h1f = out + OUT0;
    float* h2f = out + OUT0 + (size_t)BB * HH;

    // K1: x1 = A @ W_ih1^T + b_ih1  (fp32, split A + split W)
    proj_kernel<false, true><<<dim3(512), dim3(512), 0, stream>>>(
        (const void*)A, W_ih1, b_ih1, nullptr, x1);
    // K2: layer-1 scan
    scan1_kernel<<<dim3(16), dim3(256), 0, stream>>>(x1, W_hh1, b_hh1, is1, h1g, h1f);
    // K3: u = h1 @ W_ih2^T + (b_ih2 + b_hh2)  (fp32 over d_out region)
    proj_kernel<true, false><<<dim3(512), dim3(512), 0, stream>>>(
        (const void*)h1g, W_ih2, b_ih2, b_hh2, out);
    // K4: layer-2 scan, in place over u -> final outputs
    scan2_kernel<<<dim3(16), dim3(256), 0, stream>>>(out, W_hh2, is2, h2f);
}

// Round 3
// 1263.432 us; speedup vs baseline: 1.8842x; 1.8842x over previous
//
#include <hip/hip_runtime.h>

// UniRNN: T=512,B=256,X=H1=H2=256, fp32 in/out.
// R3: fp16 2-pass pipeline (replaces bf16 3-pass split-state scheme).
//   K1: x1 = A @ W_ih1^T + b_ih1        (A fp16 single, W split fp16 hi+lo)
//   K2: layer-1 scan, state single fp16 in LDS, W_hh1 split fp16; h1 -> fp16 d_ws
//   K3: u  = h1 @ W_ih2^T + b_ih2+b_hh2 (A=h1 fp16, W split fp16)
//   K4: layer-2 scan in place over u
// Rationale (R1/R2 counters): scans are LDS-pipe-bound; R2 showed cutting waves
// to 1/SIMD exposes latency. fp16 (11 mantissa bits) lets state be SINGLE
// precision -> halves per-wave LDS reads/writes and MFMA count while keeping
// 8 waves (2/SIMD). Dominant error source was already the bf16 h1 stream
// (2^-8); fp16 state noise ~2^-11/step, contractive recurrence -> absmax ~same.
// d_ws requirement: T*B*H*2 = 67,108,864 bytes (fp16 h1 stream).

#define TT 512
#define BB 256
#define HH 256
#define LSTR 280   // LDS row stride (f16 elems); 560B row = 140 dwords

typedef _Float16 f16;
typedef _Float16 f16x8 __attribute__((ext_vector_type(8)));
typedef float f32x4  __attribute__((ext_vector_type(4)));

__device__ inline float tanh_fast(float x) {
    float e = __expf(2.0f * x);
    return 1.0f - 2.0f * __builtin_amdgcn_rcpf(e + 1.0f);
}
// LDS-visibility-only barrier: waits DS ops, does NOT drain vmcnt.
__device__ inline void lds_barrier() {
    asm volatile("s_waitcnt lgkmcnt(0)\n\ts_barrier" ::: "memory");
}
// 8 consecutive fp32 -> hi/lo f16x8 fragments (split precision, RNE cvt)
__device__ inline void pack_wfrag2h(const float* __restrict__ wrow, f16x8& hi, f16x8& lo) {
    const float4* p = (const float4*)wrow;
    float4 v0 = p[0], v1 = p[1];
    float w[8] = {v0.x, v0.y, v0.z, v0.w, v1.x, v1.y, v1.z, v1.w};
#pragma unroll
    for (int i = 0; i < 8; ++i) {
        f16 h = (f16)w[i];
        hi[i] = h;
        lo[i] = (f16)(w[i] - (float)h);
    }
}
__device__ inline f32x4 mfma16h(f16x8 a, f16x8 b, f32x4 c) {
    return __builtin_amdgcn_mfma_f32_16x16x32_f16(a, b, c, 0, 0, 0);
}

// ---------------------------------------------------------------------------
// Projection GEMM: C[m,n] = sum_k A[m,k]*W[n,k] + bias(n), fp32 out.
// M = T*B = 131072, N = K = 256. Block 512 thr (8 waves), wave owns 32 cols.
// Tile 64(M) x 256(N); each WG does 4 tiles -> grid 512.
// A single fp16; W split hi+lo fp16 -> 2 MFMA passes.
// ---------------------------------------------------------------------------
template<bool IN_F16>
__global__ __launch_bounds__(512, 2)
void proj_kernel(const void* __restrict__ Ain, const float* __restrict__ W,
                 const float* __restrict__ bias_a, const float* __restrict__ bias_b,
                 float* __restrict__ Cout)
{
    __shared__ f16 lds_a[64 * LSTR];
    const int tid  = threadIdx.x;
    const int lane = tid & 63, wv = tid >> 6;
    const int quad = lane >> 4, l15 = lane & 15;
    const int n0   = wv * 32;

    f16x8 wh[2][8], wl[2][8];
    float  biasv[2];
#pragma unroll
    for (int nt = 0; nt < 2; ++nt) {
        int n = n0 + nt * 16 + l15;
        biasv[nt] = bias_a[n] + (bias_b ? bias_b[n] : 0.0f);
#pragma unroll
        for (int kc = 0; kc < 8; ++kc)
            pack_wfrag2h(W + (size_t)n * HH + kc * 32 + quad * 8, wh[nt][kc], wl[nt][kc]);
    }

    for (int it = 0; it < 4; ++it) {
        const int m0 = (blockIdx.x * 4 + it) * 64;
        if (IN_F16) {
            const unsigned short* A = (const unsigned short*)Ain;
#pragma unroll
            for (int j = 0; j < 4; ++j) {
                int c = tid + j * 512;            // 2048 chunks of 8 f16
                int row = c >> 5, col8 = c & 31;
                uint4 v = *(const uint4*)(A + (size_t)(m0 + row) * HH + col8 * 8);
                *(uint4*)&lds_a[row * LSTR + col8 * 8] = v;
            }
        } else {
            const float* A = (const float*)Ain;
#pragma unroll
            for (int j = 0; j < 8; ++j) {
                int c = tid + j * 512;            // 4096 chunks of 4 fp32
                int row = c >> 6, col4 = c & 63;
                float4 v = *(const float4*)(A + (size_t)(m0 + row) * HH + col4 * 4);
                f16 h0 = (f16)v.x, h1 = (f16)v.y, h2 = (f16)v.z, h3 = (f16)v.w;
                unsigned int p0 = (unsigned int)__builtin_bit_cast(unsigned short, h0) |
                                  ((unsigned int)__builtin_bit_cast(unsigned short, h1) << 16);
                unsigned int p1 = (unsigned int)__builtin_bit_cast(unsigned short, h2) |
                                  ((unsigned int)__builtin_bit_cast(unsigned short, h3) << 16);
                *(uint2*)&lds_a[row * LSTR + col4 * 4] = make_uint2(p0, p1);
            }
        }
        __syncthreads();

        f32x4 acc[4][2];
#pragma unroll
        for (int mt = 0; mt < 4; ++mt)
#pragma unroll
            for (int nt = 0; nt < 2; ++nt)
                acc[mt][nt] = (f32x4){0.f, 0.f, 0.f, 0.f};

#pragma unroll
        for (int kc = 0; kc < 8; ++kc) {
            f16x8 ah[4];
#pragma unroll
            for (int mt = 0; mt < 4; ++mt)
                ah[mt] = *(const f16x8*)&lds_a[(mt * 16 + l15) * LSTR + kc * 32 + quad * 8];
#pragma unroll
            for (int mt = 0; mt < 4; ++mt)
#pragma unroll
                for (int nt = 0; nt < 2; ++nt) {
                    acc[mt][nt] = mfma16h(ah[mt], wh[nt][kc], acc[mt][nt]);
                    acc[mt][nt] = mfma16h(ah[mt], wl[nt][kc], acc[mt][nt]);
                }
        }

#pragma unroll
        for (int mt = 0; mt < 4; ++mt)
#pragma unroll
            for (int nt = 0; nt < 2; ++nt)
#pragma unroll
                for (int r = 0; r < 4; ++r) {
                    int row = m0 + mt * 16 + quad * 4 + r;
                    int col = n0 + nt * 16 + l15;
                    Cout[(size_t)row * HH + col] = acc[mt][nt][r] + biasv[nt];
                }
        __syncthreads();
    }
}

// ---------------------------------------------------------------------------
// Layer-1 scan: 16 WGs x 512 thr (8 waves, 2/SIMD). WG owns batch rows
// [m0,m0+16), wave owns 32 cols. State SINGLE fp16 in LDS (double-buffered),
// W_hh1 split fp16 in 128 VGPRs. 2 MFMA passes/step: h@Whi + h@Wlo.
// Per-CU LDS state reads: 8 waves x 8KB = 64KB/step (R1 was 128KB).
// ---------------------------------------------------------------------------
__global__ __launch_bounds__(512, 2)
void scan1_kernel(const float* __restrict__ x1,             // [T,B,H] fp32
                  const float* __restrict__ Whh1,
                  const float* __restrict__ bhh1,
                  const float* __restrict__ h0,             // [B,H] fp32
                  f16* __restrict__ h1g,                    // [T,B,H] fp16 out
                  float* __restrict__ h1f)                  // [B,H] fp32 final
{
    __shared__ f16 hs[2][16 * LSTR];
    const int tid  = threadIdx.x;
    const int lane = tid & 63, wv = tid >> 6;
    const int quad = lane >> 4, l15 = lane & 15;
    const int m0   = blockIdx.x * 16;
    const int n0   = wv * 32;

    f16x8 wh[2][8], wl[2][8];
    float  biasv[2];
#pragma unroll
    for (int nt = 0; nt < 2; ++nt) {
        int n = n0 + nt * 16 + l15;
        biasv[nt] = bhh1[n];
#pragma unroll
        for (int kc = 0; kc < 8; ++kc)
            pack_wfrag2h(Whh1 + (size_t)n * HH + kc * 32 + quad * 8, wh[nt][kc], wl[nt][kc]);
    }
#pragma unroll
    for (int j = 0; j < 8; ++j) {
        int idx = tid + j * 512;
        int row = idx >> 8, col = idx & 255;
        hs[0][row * LSTR + col] = (f16)h0[(size_t)(m0 + row) * HH + col];
    }
    __syncthreads();

    const int colb = n0 + l15;
    const int rowb = quad * 4;

    // prefetch x(t=0)
    float xc[2][4];
#pragma unroll
    for (int nt = 0; nt < 2; ++nt)
#pragma unroll
        for (int r = 0; r < 4; ++r)
            xc[nt][r] = x1[(size_t)(m0 + rowb + r) * HH + colb + nt * 16];

    for (int t = 0; t < TT; ++t) {
        const int cur = t & 1, nxt = (t + 1) & 1;
        const size_t base = ((size_t)t * BB + m0) * HH;
        const int tn = (t + 1 < TT) ? (t + 1) : t;          // clamp (unused on last)
        const size_t basen = ((size_t)tn * BB + m0) * HH;

        // prefetch x(t+1): consumed one full step later
        float xn[2][4];
#pragma unroll
        for (int nt = 0; nt < 2; ++nt)
#pragma unroll
            for (int r = 0; r < 4; ++r)
                xn[nt][r] = x1[basen + (size_t)(rowb + r) * HH + colb + nt * 16];

        f32x4 accA[2] = {(f32x4){0.f,0.f,0.f,0.f}, (f32x4){0.f,0.f,0.f,0.f}};
        f32x4 accB[2] = {(f32x4){0.f,0.f,0.f,0.f}, (f32x4){0.f,0.f,0.f,0.f}};
#pragma unroll
        for (int kc = 0; kc < 4; ++kc) {
            const int kd = kc + 4;
            f16x8 ahA = *(const f16x8*)&hs[cur][l15 * LSTR + kc * 32 + quad * 8];
            f16x8 ahB = *(const f16x8*)&hs[cur][l15 * LSTR + kd * 32 + quad * 8];
#pragma unroll
            for (int nt = 0; nt < 2; ++nt) {
                accA[nt] = mfma16h(ahA, wh[nt][kc], accA[nt]);
                accA[nt] = mfma16h(ahA, wl[nt][kc], accA[nt]);
                accB[nt] = mfma16h(ahB, wh[nt][kd], accB[nt]);
                accB[nt] = mfma16h(ahB, wl[nt][kd], accB[nt]);
            }
        }

#pragma unroll
        for (int nt = 0; nt < 2; ++nt) {
            f32x4 acc = accA[nt] + accB[nt];
#pragma unroll
            for (int r = 0; r < 4; ++r) {
                float pre = acc[r] + xc[nt][r] + biasv[nt];
                float h   = tanh_fast(pre);
                f16 hb    = (f16)h;
                int row = rowb + r, col = colb + nt * 16;
                hs[nxt][row * LSTR + col] = hb;
                h1g[base + (size_t)row * HH + col] = hb;
                if (t == TT - 1) h1f[(size_t)(m0 + row) * HH + col] = h;
            }
        }
        lds_barrier();
#pragma unroll
        for (int nt = 0; nt < 2; ++nt)
#pragma unroll
            for (int r = 0; r < 4; ++r)
                xc[nt][r] = xn[nt][r];
    }
}

// ---------------------------------------------------------------------------
// Layer-2 scan: same structure; u fp32 in/out in place (biases pre-folded).
// ---------------------------------------------------------------------------
__global__ __launch_bounds__(512, 2)
void scan2_kernel(float* __restrict__ u,                    // [T,B,H] fp32, in/out
                  const float* __restrict__ Whh2,
                  const float* __restrict__ h0,             // [B,H] fp32
                  float* __restrict__ h2f)                  // [B,H] fp32 final
{
    __shared__ f16 hs[2][16 * LSTR];
    const int tid  = threadIdx.x;
    const int lane = tid & 63, wv = tid >> 6;
    const int quad = lane >> 4, l15 = lane & 15;
    const int m0   = blockIdx.x * 16;
    const int n0   = wv * 32;

    f16x8 wh[2][8], wl[2][8];
#pragma unroll
    for (int nt = 0; nt < 2; ++nt) {
        int n = n0 + nt * 16 + l15;
#pragma unroll
        for (int kc = 0; kc < 8; ++kc)
            pack_wfrag2h(Whh2 + (size_t)n * HH + kc * 32 + quad * 8, wh[nt][kc], wl[nt][kc]);
    }
#pragma unroll
    for (int j = 0; j < 8; ++j) {
        int idx = tid + j * 512;
        int row = idx >> 8, col = idx & 255;
        hs[0][row * LSTR + col] = (f16)h0[(size_t)(m0 + row) * HH + col];
    }
    __syncthreads();

    const int colb = n0 + l15;
    const int rowb = quad * 4;

    // prefetch u(t=0)
    float uc[2][4];
#pragma unroll
    for (int nt = 0; nt < 2; ++nt)
#pragma unroll
        for (int r = 0; r < 4; ++r)
            uc[nt][r] = u[(size_t)(m0 + rowb + r) * HH + colb + nt * 16];

    for (int t = 0; t < TT; ++t) {
        const int cur = t & 1, nxt = (t + 1) & 1;
        const size_t base = ((size_t)t * BB + m0) * HH;
        const int tn = (t + 1 < TT) ? (t + 1) : t;
        const size_t basen = ((size_t)tn * BB + m0) * HH;

        // prefetch u(t+1); last iter reads u(t) BEFORE this step's in-place
        // write (per-lane program order) -> stale values, discarded. Safe.
        float un[2][4];
#pragma unroll
        for (int nt = 0; nt < 2; ++nt)
#pragma unroll
            for (int r = 0; r < 4; ++r)
                un[nt][r] = u[basen + (size_t)(rowb + r) * HH + colb + nt * 16];

        f32x4 accA[2] = {(f32x4){0.f,0.f,0.f,0.f}, (f32x4){0.f,0.f,0.f,0.f}};
        f32x4 accB[2] = {(f32x4){0.f,0.f,0.f,0.f}, (f32x4){0.f,0.f,0.f,0.f}};
#pragma unroll
        for (int kc = 0; kc < 4; ++kc) {
            const int kd = kc + 4;
            f16x8 ahA = *(const f16x8*)&hs[cur][l15 * LSTR + kc * 32 + quad * 8];
            f16x8 ahB = *(const f16x8*)&hs[cur][l15 * LSTR + kd * 32 + quad * 8];
#pragma unroll
            for (int nt = 0; nt < 2; ++nt) {
                accA[nt] = mfma16h(ahA, wh[nt][kc], accA[nt]);
                accA[nt] = mfma16h(ahA, wl[nt][kc], accA[nt]);
                accB[nt] = mfma16h(ahB, wh[nt][kd], accB[nt]);
                accB[nt] = mfma16h(ahB, wl[nt][kd], accB[nt]);
            }
        }

#pragma unroll
        for (int nt = 0; nt < 2; ++nt) {
            f32x4 acc = accA[nt] + accB[nt];
#pragma unroll
            for (int r = 0; r < 4; ++r) {
                float pre = acc[r] + uc[nt][r];
                float h   = tanh_fast(pre);
                int row = rowb + r, col = colb + nt * 16;
                hs[nxt][row * LSTR + col] = (f16)h;
                u[base + (size_t)row * HH + col] = h;       // final output
                if (t == TT - 1) h2f[(size_t)(m0 + row) * HH + col] = h;
            }
        }
        lds_barrier();
#pragma unroll
        for (int nt = 0; nt < 2; ++nt)
#pragma unroll
            for (int r = 0; r < 4; ++r)
                uc[nt][r] = un[nt][r];
    }
}

extern "C" void kernel_launch(void* const* d_in, const int* in_sizes, int n_in,
                              void* d_out, int out_size, void* d_ws, size_t ws_size,
                              hipStream_t stream)
{
    const float* A     = (const float*)d_in[0];   // [T,B,X]
    const float* is1   = (const float*)d_in[1];   // [B,H1]
    const float* is2   = (const float*)d_in[2];   // [B,H2]
    const float* W_ih1 = (const float*)d_in[3];
    const float* W_hh1 = (const float*)d_in[4];
    const float* b_ih1 = (const float*)d_in[5];
    const float* b_hh1 = (const float*)d_in[6];
    const float* W_ih2 = (const float*)d_in[7];
    const float* W_hh2 = (const float*)d_in[8];
    const float* b_ih2 = (const float*)d_in[9];
    const float* b_hh2 = (const float*)d_in[10];

    float* out = (float*)d_out;
    const size_t OUT0 = (size_t)TT * BB * HH;          // 33554432
    float* x1  = out;                                  // fp32 scratch in out region
    f16*   h1g = (f16*)d_ws;                           // fp16 h1 stream, 67 MB
    float* h1f = out + OUT0;
    float* h2f = out + OUT0 + (size_t)BB * HH;

    // K1: x1 = A @ W_ih1^T + b_ih1  (A fp16, W split fp16, 2-pass)
    proj_kernel<false><<<dim3(512), dim3(512), 0, stream>>>(
        (const void*)A, W_ih1, b_ih1, nullptr, x1);
    // K2: layer-1 scan
    scan1_kernel<<<dim3(16), dim3(512), 0, stream>>>(x1, W_hh1, b_hh1, is1, h1g, h1f);
    // K3: u = h1 @ W_ih2^T + (b_ih2 + b_hh2)
    proj_kernel<true><<<dim3(512), dim3(512), 0, stream>>>(
        (const void*)h1g, W_ih2, b_ih2, b_hh2, out);
    // K4: layer-2 scan, in place over u -> final outputs
    scan2_kernel<<<dim3(16), dim3(512), 0, stream>>>(out, W_hh2, is2, h2f);
}

// Round 4
// 1165.739 us; speedup vs baseline: 2.0421x; 1.0838x over previous
//
#include <hip/hip_runtime.h>

// UniRNN: T=512,B=256,X=H1=H2=256, fp32 in/out.
// R4: FUSED recurrent pipeline.
//   K1: x1 = A @ W_ih1^T + b_ih1   (fp32->f16 staging, single-f16 W, fp32 out)
//   K2: fused scan: per step t (per WG = 16 batch rows):
//         h1 = tanh(x1(t) + h1@W_hh1^T + b_hh1)            [GEMM1]
//         h2 = tanh(h1@W_ih2^T + h2@W_hh2^T + b_ih2+b_hh2) [GEMM2+GEMM3]
//       -> writes h2 into out in place over x1(t) (read-then-write, same WG).
// Eliminates: K3 projection kernel, scan2 serial pass, h1g stream (134MB),
// u materialization (268MB). d_ws now unused.
// Numerics: ALL W single fp16 (VGPR: 3x64=192 W-frags fits 256/wave @2 waves/
// SIMD; split-W would be 320+ -> spill). State fp16 in LDS. fp32 acc + fp32
// x/out path. Expected absmax ~5e-3 (R3: 3.9e-3; pass line >= 7.8e-3).

#define TT 512
#define BB 256
#define HH 256
#define LSTR 280   // LDS row stride (f16 elems); 560B row keeps b128 reads 16B-aligned

typedef _Float16 f16;
typedef _Float16 f16x8 __attribute__((ext_vector_type(8)));
typedef float f32x4  __attribute__((ext_vector_type(4)));

__device__ inline float tanh_fast(float x) {
    float e = __expf(2.0f * x);
    return 1.0f - 2.0f * __builtin_amdgcn_rcpf(e + 1.0f);
}
// LDS-visibility-only barrier: waits DS ops, does NOT drain vmcnt.
__device__ inline void lds_barrier() {
    asm volatile("s_waitcnt lgkmcnt(0)\n\ts_barrier" ::: "memory");
}
// 8 consecutive fp32 -> single f16x8 fragment (RNE)
__device__ inline f16x8 pack_wfragh(const float* __restrict__ wrow) {
    const float4* p = (const float4*)wrow;
    float4 v0 = p[0], v1 = p[1];
    f16x8 h;
    h[0] = (f16)v0.x; h[1] = (f16)v0.y; h[2] = (f16)v0.z; h[3] = (f16)v0.w;
    h[4] = (f16)v1.x; h[5] = (f16)v1.y; h[6] = (f16)v1.z; h[7] = (f16)v1.w;
    return h;
}
__device__ inline f32x4 mfma16h(f16x8 a, f16x8 b, f32x4 c) {
    return __builtin_amdgcn_mfma_f32_16x16x32_f16(a, b, c, 0, 0, 0);
}

// ---------------------------------------------------------------------------
// K1 projection: x1[m,n] = sum_k A[m,k]*W_ih1[n,k] + b_ih1[n], fp32 out.
// M = T*B = 131072, N = K = 256. 512 thr (8 waves), wave owns 32 cols.
// Tile 64(M) x 256(N); each WG does 4 tiles -> grid 512. Single-f16 W, 1 pass.
// ---------------------------------------------------------------------------
__global__ __launch_bounds__(512, 2)
void proj_kernel(const float* __restrict__ Ain, const float* __restrict__ W,
                 const float* __restrict__ bias, float* __restrict__ Cout)
{
    __shared__ f16 lds_a[64 * LSTR];
    const int tid  = threadIdx.x;
    const int lane = tid & 63, wv = tid >> 6;
    const int quad = lane >> 4, l15 = lane & 15;
    const int n0   = wv * 32;

    f16x8 wh[2][8];
    float biasv[2];
#pragma unroll
    for (int nt = 0; nt < 2; ++nt) {
        int n = n0 + nt * 16 + l15;
        biasv[nt] = bias[n];
#pragma unroll
        for (int kc = 0; kc < 8; ++kc)
            wh[nt][kc] = pack_wfragh(W + (size_t)n * HH + kc * 32 + quad * 8);
    }

    for (int it = 0; it < 4; ++it) {
        const int m0 = (blockIdx.x * 4 + it) * 64;
#pragma unroll
        for (int j = 0; j < 8; ++j) {
            int c = tid + j * 512;            // 4096 chunks of 4 fp32
            int row = c >> 6, col4 = c & 63;
            float4 v = *(const float4*)(Ain + (size_t)(m0 + row) * HH + col4 * 4);
            f16 h0 = (f16)v.x, h1 = (f16)v.y, h2 = (f16)v.z, h3 = (f16)v.w;
            unsigned int p0 = (unsigned int)__builtin_bit_cast(unsigned short, h0) |
                              ((unsigned int)__builtin_bit_cast(unsigned short, h1) << 16);
            unsigned int p1 = (unsigned int)__builtin_bit_cast(unsigned short, h2) |
                              ((unsigned int)__builtin_bit_cast(unsigned short, h3) << 16);
            *(uint2*)&lds_a[row * LSTR + col4 * 4] = make_uint2(p0, p1);
        }
        __syncthreads();

        f32x4 acc[4][2];
#pragma unroll
        for (int mt = 0; mt < 4; ++mt)
#pragma unroll
            for (int nt = 0; nt < 2; ++nt)
                acc[mt][nt] = (f32x4){0.f, 0.f, 0.f, 0.f};

#pragma unroll
        for (int kc = 0; kc < 8; ++kc) {
            f16x8 ah[4];
#pragma unroll
            for (int mt = 0; mt < 4; ++mt)
                ah[mt] = *(const f16x8*)&lds_a[(mt * 16 + l15) * LSTR + kc * 32 + quad * 8];
#pragma unroll
            for (int mt = 0; mt < 4; ++mt)
#pragma unroll
                for (int nt = 0; nt < 2; ++nt)
                    acc[mt][nt] = mfma16h(ah[mt], wh[nt][kc], acc[mt][nt]);
        }

#pragma unroll
        for (int mt = 0; mt < 4; ++mt)
#pragma unroll
            for (int nt = 0; nt < 2; ++nt)
#pragma unroll
                for (int r = 0; r < 4; ++r) {
                    int row = m0 + mt * 16 + quad * 4 + r;
                    int col = n0 + nt * 16 + l15;
                    Cout[(size_t)row * HH + col] = acc[mt][nt][r] + biasv[nt];
                }
        __syncthreads();
    }
}

// ---------------------------------------------------------------------------
// Fused scan: 16 WGs x 512 thr (8 waves, 2/SIMD). WG owns batch rows
// [m0,m0+16), wave owns 32 cols (2 nt). States h1,h2 single fp16 in LDS
// (double-buffered). W_hh1/W_ih2/W_hh2 single fp16 in VGPRs (64 each).
// Per step: phase A = GEMM1(h1@W1) + GEMM3(h2@W3) interleaved (independent),
// epilogue-1 writes new h1 -> barrier -> phase B = GEMM2(h1new@W2), epilogue-2
// writes new h2 to LDS and to out (in place over consumed x1(t)) -> barrier.
// ---------------------------------------------------------------------------
__global__ __launch_bounds__(512, 2)
void fused_scan_kernel(float* __restrict__ xu,            // [T,B,H] fp32: in x1, out h2
                       const float* __restrict__ Whh1,
                       const float* __restrict__ bhh1,
                       const float* __restrict__ Wih2,
                       const float* __restrict__ Whh2,
                       const float* __restrict__ bih2,
                       const float* __restrict__ bhh2,
                       const float* __restrict__ h10,     // [B,H] fp32
                       const float* __restrict__ h20,     // [B,H] fp32
                       float* __restrict__ h1f,           // [B,H] fp32 final
                       float* __restrict__ h2f)           // [B,H] fp32 final
{
    __shared__ f16 hs1[2][16 * LSTR];
    __shared__ f16 hs2[2][16 * LSTR];
    const int tid  = threadIdx.x;
    const int lane = tid & 63, wv = tid >> 6;
    const int quad = lane >> 4, l15 = lane & 15;
    const int m0   = blockIdx.x * 16;
    const int n0   = wv * 32;

    f16x8 w1[2][8], w2[2][8], w3[2][8];
    float b1v[2], b2v[2];
#pragma unroll
    for (int nt = 0; nt < 2; ++nt) {
        int n = n0 + nt * 16 + l15;
        b1v[nt] = bhh1[n];
        b2v[nt] = bih2[n] + bhh2[n];
#pragma unroll
        for (int kc = 0; kc < 8; ++kc) {
            w1[nt][kc] = pack_wfragh(Whh1 + (size_t)n * HH + kc * 32 + quad * 8);
            w2[nt][kc] = pack_wfragh(Wih2 + (size_t)n * HH + kc * 32 + quad * 8);
            w3[nt][kc] = pack_wfragh(Whh2 + (size_t)n * HH + kc * 32 + quad * 8);
        }
    }
#pragma unroll
    for (int j = 0; j < 8; ++j) {
        int idx = tid + j * 512;
        int row = idx >> 8, col = idx & 255;
        hs1[0][row * LSTR + col] = (f16)h10[(size_t)(m0 + row) * HH + col];
        hs2[0][row * LSTR + col] = (f16)h20[(size_t)(m0 + row) * HH + col];
    }
    __syncthreads();

    const int colb = n0 + l15;
    const int rowb = quad * 4;

    for (int t = 0; t < TT; ++t) {
        const int cur = t & 1, nxt = (t + 1) & 1;
        const size_t base = ((size_t)t * BB + m0) * HH;

        // Issue x1(t) loads now; first use is after phase A (~covers HBM lat).
        float xc[2][4];
#pragma unroll
        for (int nt = 0; nt < 2; ++nt)
#pragma unroll
            for (int r = 0; r < 4; ++r)
                xc[nt][r] = xu[base + (size_t)(rowb + r) * HH + colb + nt * 16];

        // Phase A: GEMM1 (h1@W_hh1) + GEMM3 (h2@W_hh2), independent chains.
        f32x4 acc1[2] = {(f32x4){0.f,0.f,0.f,0.f}, (f32x4){0.f,0.f,0.f,0.f}};
        f32x4 acc3[2] = {(f32x4){0.f,0.f,0.f,0.f}, (f32x4){0.f,0.f,0.f,0.f}};
#pragma unroll
        for (int kc = 0; kc < 8; ++kc) {
            f16x8 a1 = *(const f16x8*)&hs1[cur][l15 * LSTR + kc * 32 + quad * 8];
            f16x8 a3 = *(const f16x8*)&hs2[cur][l15 * LSTR + kc * 32 + quad * 8];
#pragma unroll
            for (int nt = 0; nt < 2; ++nt) {
                acc1[nt] = mfma16h(a1, w1[nt][kc], acc1[nt]);
                acc3[nt] = mfma16h(a3, w3[nt][kc], acc3[nt]);
            }
        }

        // Epilogue 1: h1(t) -> hs1[nxt]
#pragma unroll
        for (int nt = 0; nt < 2; ++nt)
#pragma unroll
            for (int r = 0; r < 4; ++r) {
                float pre = acc1[nt][r] + xc[nt][r] + b1v[nt];
                float h   = tanh_fast(pre);
                hs1[nxt][(rowb + r) * LSTR + colb + nt * 16] = (f16)h;
                if (t == TT - 1)
                    h1f[(size_t)(m0 + rowb + r) * HH + colb + nt * 16] = h;
            }
        lds_barrier();

        // Phase B: GEMM2 (h1(t) @ W_ih2)
        f32x4 acc2[2] = {(f32x4){0.f,0.f,0.f,0.f}, (f32x4){0.f,0.f,0.f,0.f}};
#pragma unroll
        for (int kc = 0; kc < 8; ++kc) {
            f16x8 a2 = *(const f16x8*)&hs1[nxt][l15 * LSTR + kc * 32 + quad * 8];
#pragma unroll
            for (int nt = 0; nt < 2; ++nt)
                acc2[nt] = mfma16h(a2, w2[nt][kc], acc2[nt]);
        }

        // Epilogue 2: h2(t) -> hs2[nxt], out (in place over consumed x1(t))
#pragma unroll
        for (int nt = 0; nt < 2; ++nt)
#pragma unroll
            for (int r = 0; r < 4; ++r) {
                float pre = acc2[nt][r] + acc3[nt][r] + b2v[nt];
                float h   = tanh_fast(pre);
                hs2[nxt][(rowb + r) * LSTR + colb + nt * 16] = (f16)h;
                xu[base + (size_t)(rowb + r) * HH + colb + nt * 16] = h;
                if (t == TT - 1)
                    h2f[(size_t)(m0 + rowb + r) * HH + colb + nt * 16] = h;
            }
        lds_barrier();
    }
}

extern "C" void kernel_launch(void* const* d_in, const int* in_sizes, int n_in,
                              void* d_out, int out_size, void* d_ws, size_t ws_size,
                              hipStream_t stream)
{
    const float* A     = (const float*)d_in[0];   // [T,B,X]
    const float* is1   = (const float*)d_in[1];   // [B,H1]
    const float* is2   = (const float*)d_in[2];   // [B,H2]
    const float* W_ih1 = (const float*)d_in[3];
    const float* W_hh1 = (const float*)d_in[4];
    const float* b_ih1 = (const float*)d_in[5];
    const float* b_hh1 = (const float*)d_in[6];
    const float* W_ih2 = (const float*)d_in[7];
    const float* W_hh2 = (const float*)d_in[8];
    const float* b_ih2 = (const float*)d_in[9];
    const float* b_hh2 = (const float*)d_in[10];

    float* out = (float*)d_out;
    const size_t OUT0 = (size_t)TT * BB * HH;          // 33554432
    float* x1  = out;                                  // fp32 scratch in out region
    float* h1f = out + OUT0;
    float* h2f = out + OUT0 + (size_t)BB * HH;
    (void)d_ws; (void)ws_size;                         // unused in R4

    // K1: x1 = A @ W_ih1^T + b_ih1  (single-f16 W, 1 pass)
    proj_kernel<<<dim3(512), dim3(512), 0, stream>>>(A, W_ih1, b_ih1, x1);
    // K2: fused scan (layer1 + u-projection + layer2), in place over x1 -> out
    fused_scan_kernel<<<dim3(16), dim3(512), 0, stream>>>(
        x1, W_hh1, b_hh1, W_ih2, W_hh2, b_ih2, b_hh2, is1, is2, h1f, h2f);
}

// Round 5
// 1069.721 us; speedup vs baseline: 2.2254x; 1.0898x over previous
//
#include <hip/hip_runtime.h>

// UniRNN: T=512,B=256,X=H1=H2=256, fp32 in/out.
// R5: fused scan with MERGED phase (single barrier/step).
//   K1: x1 = A @ W_ih1^T + b_ih1   (single-f16 W, fp32 out)
//   K2: fused scan, re-indexed: phase i computes
//         h2(i)   = tanh(h1(i)@W_ih2 + h2(i-1)@W_hh2 + b2)
//         h1(i+1) = tanh(h1(i)@W_hh1 + x(i+1) + b1)
//       so the a1 = h1(i) LDS fragments are read ONCE and feed BOTH w2 and w1
//       MFMAs (R4 read them twice across two barrier-separated phases).
//   LDS reads/wave/step: 24 -> 16 b128; barriers 2 -> 1; MFMA same (24,
//   6 independent 8-deep chains). Numerics identical to R4 (same ops).
// R4 counters: step ~4320 cyc, ~90% LDS-pipe (192 b128 + 128 writes + 768
// conflict cyc per CU/step); MFMA only ~230 cyc/SIMD. This cuts the read
// term by 1/3 and halves barrier drains.

#define TT 512
#define BB 256
#define HH 256
#define LSTR 280   // LDS row stride (f16 elems); 560B row keeps b128 reads 16B-aligned

typedef _Float16 f16;
typedef _Float16 f16x8 __attribute__((ext_vector_type(8)));
typedef float f32x4  __attribute__((ext_vector_type(4)));

__device__ inline float tanh_fast(float x) {
    float e = __expf(2.0f * x);
    return 1.0f - 2.0f * __builtin_amdgcn_rcpf(e + 1.0f);
}
// LDS-visibility-only barrier: waits DS ops, does NOT drain vmcnt.
__device__ inline void lds_barrier() {
    asm volatile("s_waitcnt lgkmcnt(0)\n\ts_barrier" ::: "memory");
}
// 8 consecutive fp32 -> single f16x8 fragment (RNE)
__device__ inline f16x8 pack_wfragh(const float* __restrict__ wrow) {
    const float4* p = (const float4*)wrow;
    float4 v0 = p[0], v1 = p[1];
    f16x8 h;
    h[0] = (f16)v0.x; h[1] = (f16)v0.y; h[2] = (f16)v0.z; h[3] = (f16)v0.w;
    h[4] = (f16)v1.x; h[5] = (f16)v1.y; h[6] = (f16)v1.z; h[7] = (f16)v1.w;
    return h;
}
__device__ inline f32x4 mfma16h(f16x8 a, f16x8 b, f32x4 c) {
    return __builtin_amdgcn_mfma_f32_16x16x32_f16(a, b, c, 0, 0, 0);
}

// ---------------------------------------------------------------------------
// K1 projection: x1[m,n] = sum_k A[m,k]*W_ih1[n,k] + b_ih1[n], fp32 out.
// M = T*B = 131072, N = K = 256. 512 thr (8 waves), wave owns 32 cols.
// Tile 64(M) x 256(N); each WG does 4 tiles -> grid 512. Single-f16 W, 1 pass.
// ---------------------------------------------------------------------------
__global__ __launch_bounds__(512, 2)
void proj_kernel(const float* __restrict__ Ain, const float* __restrict__ W,
                 const float* __restrict__ bias, float* __restrict__ Cout)
{
    __shared__ f16 lds_a[64 * LSTR];
    const int tid  = threadIdx.x;
    const int lane = tid & 63, wv = tid >> 6;
    const int quad = lane >> 4, l15 = lane & 15;
    const int n0   = wv * 32;

    f16x8 wh[2][8];
    float biasv[2];
#pragma unroll
    for (int nt = 0; nt < 2; ++nt) {
        int n = n0 + nt * 16 + l15;
        biasv[nt] = bias[n];
#pragma unroll
        for (int kc = 0; kc < 8; ++kc)
            wh[nt][kc] = pack_wfragh(W + (size_t)n * HH + kc * 32 + quad * 8);
    }

    for (int it = 0; it < 4; ++it) {
        const int m0 = (blockIdx.x * 4 + it) * 64;
#pragma unroll
        for (int j = 0; j < 8; ++j) {
            int c = tid + j * 512;            // 4096 chunks of 4 fp32
            int row = c >> 6, col4 = c & 63;
            float4 v = *(const float4*)(Ain + (size_t)(m0 + row) * HH + col4 * 4);
            f16 h0 = (f16)v.x, h1 = (f16)v.y, h2 = (f16)v.z, h3 = (f16)v.w;
            unsigned int p0 = (unsigned int)__builtin_bit_cast(unsigned short, h0) |
                              ((unsigned int)__builtin_bit_cast(unsigned short, h1) << 16);
            unsigned int p1 = (unsigned int)__builtin_bit_cast(unsigned short, h2) |
                              ((unsigned int)__builtin_bit_cast(unsigned short, h3) << 16);
            *(uint2*)&lds_a[row * LSTR + col4 * 4] = make_uint2(p0, p1);
        }
        __syncthreads();

        f32x4 acc[4][2];
#pragma unroll
        for (int mt = 0; mt < 4; ++mt)
#pragma unroll
            for (int nt = 0; nt < 2; ++nt)
                acc[mt][nt] = (f32x4){0.f, 0.f, 0.f, 0.f};

#pragma unroll
        for (int kc = 0; kc < 8; ++kc) {
            f16x8 ah[4];
#pragma unroll
            for (int mt = 0; mt < 4; ++mt)
                ah[mt] = *(const f16x8*)&lds_a[(mt * 16 + l15) * LSTR + kc * 32 + quad * 8];
#pragma unroll
            for (int mt = 0; mt < 4; ++mt)
#pragma unroll
                for (int nt = 0; nt < 2; ++nt)
                    acc[mt][nt] = mfma16h(ah[mt], wh[nt][kc], acc[mt][nt]);
        }

#pragma unroll
        for (int mt = 0; mt < 4; ++mt)
#pragma unroll
            for (int nt = 0; nt < 2; ++nt)
#pragma unroll
                for (int r = 0; r < 4; ++r) {
                    int row = m0 + mt * 16 + quad * 4 + r;
                    int col = n0 + nt * 16 + l15;
                    Cout[(size_t)row * HH + col] = acc[mt][nt][r] + biasv[nt];
                }
        __syncthreads();
    }
}

// ---------------------------------------------------------------------------
// Fused scan, merged phase: 16 WGs x 512 thr (8 waves, 2/SIMD). WG owns
// batch rows [m0,m0+16), wave owns 32 cols (2 nt). States h1,h2 fp16 in LDS,
// double-buffered. W_hh1/W_ih2/W_hh2 single fp16 in regs (64 frags each).
// Phase i: read a1=h1(i), a2=h2(i-1) once; 24 MFMA into acc2/acc1/acc3;
// epilogue writes h2(i) (LDS+global) and h1(i+1) (LDS); ONE barrier.
// ---------------------------------------------------------------------------
__global__ __launch_bounds__(512, 2)
void fused_scan_kernel(float* __restrict__ xu,            // [T,B,H] fp32: in x1, out h2
                       const float* __restrict__ Whh1,
                       const float* __restrict__ bhh1,
                       const float* __restrict__ Wih2,
                       const float* __restrict__ Whh2,
                       const float* __restrict__ bih2,
                       const float* __restrict__ bhh2,
                       const float* __restrict__ h10,     // [B,H] fp32
                       const float* __restrict__ h20,     // [B,H] fp32
                       float* __restrict__ h1f,           // [B,H] fp32 final
                       float* __restrict__ h2f)           // [B,H] fp32 final
{
    __shared__ f16 hs1[2][16 * LSTR];
    __shared__ f16 hs2[2][16 * LSTR];
    const int tid  = threadIdx.x;
    const int lane = tid & 63, wv = tid >> 6;
    const int quad = lane >> 4, l15 = lane & 15;
    const int m0   = blockIdx.x * 16;
    const int n0   = wv * 32;

    f16x8 w1[2][8], w2[2][8], w3[2][8];
    float b1v[2], b2v[2];
#pragma unroll
    for (int nt = 0; nt < 2; ++nt) {
        int n = n0 + nt * 16 + l15;
        b1v[nt] = bhh1[n];
        b2v[nt] = bih2[n] + bhh2[n];
#pragma unroll
        for (int kc = 0; kc < 8; ++kc) {
            w1[nt][kc] = pack_wfragh(Whh1 + (size_t)n * HH + kc * 32 + quad * 8);
            w2[nt][kc] = pack_wfragh(Wih2 + (size_t)n * HH + kc * 32 + quad * 8);
            w3[nt][kc] = pack_wfragh(Whh2 + (size_t)n * HH + kc * 32 + quad * 8);
        }
    }
    // init: is1 -> hs1[1] (consumed by prologue GEMM), is2 -> hs2[0]
    // (phase 0 reads h2(-1) from hs2[0]).
#pragma unroll
    for (int j = 0; j < 8; ++j) {
        int idx = tid + j * 512;
        int row = idx >> 8, col = idx & 255;
        hs1[1][row * LSTR + col] = (f16)h10[(size_t)(m0 + row) * HH + col];
        hs2[0][row * LSTR + col] = (f16)h20[(size_t)(m0 + row) * HH + col];
    }
    __syncthreads();

    const int colb = n0 + l15;
    const int rowb = quad * 4;

    // Prologue: h1(0) = tanh(x(0) + is1@W_hh1 + b1) -> hs1[0]
    {
        float x0[2][4];
#pragma unroll
        for (int nt = 0; nt < 2; ++nt)
#pragma unroll
            for (int r = 0; r < 4; ++r)
                x0[nt][r] = xu[(size_t)(m0 + rowb + r) * HH + colb + nt * 16];

        f32x4 p[2] = {(f32x4){0.f,0.f,0.f,0.f}, (f32x4){0.f,0.f,0.f,0.f}};
#pragma unroll
        for (int kc = 0; kc < 8; ++kc) {
            f16x8 a = *(const f16x8*)&hs1[1][l15 * LSTR + kc * 32 + quad * 8];
#pragma unroll
            for (int nt = 0; nt < 2; ++nt)
                p[nt] = mfma16h(a, w1[nt][kc], p[nt]);
        }
#pragma unroll
        for (int nt = 0; nt < 2; ++nt)
#pragma unroll
            for (int r = 0; r < 4; ++r) {
                float h = tanh_fast(p[nt][r] + x0[nt][r] + b1v[nt]);
                hs1[0][(rowb + r) * LSTR + colb + nt * 16] = (f16)h;
            }
        __syncthreads();
    }

    // Main loop: phase i computes h2(i) and h1(i+1), one barrier.
    for (int i = 0; i < TT; ++i) {
        const int cur = i & 1, nxt = cur ^ 1;
        const size_t basew = ((size_t)i * BB + m0) * HH;               // h2(i) out
        const int ir = (i + 1 < TT) ? (i + 1) : i;                     // clamp
        const size_t baser = ((size_t)ir * BB + m0) * HH;              // x(i+1) in

        // x(i+1): issued early; 24 MFMA + 16 ds_reads cover the HBM latency.
        float xn[2][4];
#pragma unroll
        for (int nt = 0; nt < 2; ++nt)
#pragma unroll
            for (int r = 0; r < 4; ++r)
                xn[nt][r] = xu[baser + (size_t)(rowb + r) * HH + colb + nt * 16];

        f32x4 acc1[2] = {(f32x4){0.f,0.f,0.f,0.f}, (f32x4){0.f,0.f,0.f,0.f}};
        f32x4 acc2[2] = {(f32x4){0.f,0.f,0.f,0.f}, (f32x4){0.f,0.f,0.f,0.f}};
        f32x4 acc3[2] = {(f32x4){0.f,0.f,0.f,0.f}, (f32x4){0.f,0.f,0.f,0.f}};
#pragma unroll
        for (int kc = 0; kc < 8; ++kc) {
            f16x8 a1 = *(const f16x8*)&hs1[cur][l15 * LSTR + kc * 32 + quad * 8];
            f16x8 a2 = *(const f16x8*)&hs2[cur][l15 * LSTR + kc * 32 + quad * 8];
#pragma unroll
            for (int nt = 0; nt < 2; ++nt) {
                acc2[nt] = mfma16h(a1, w2[nt][kc], acc2[nt]);   // u(i)   = h1(i)@W_ih2
                acc1[nt] = mfma16h(a1, w1[nt][kc], acc1[nt]);   // pre-h1(i+1)
                acc3[nt] = mfma16h(a2, w3[nt][kc], acc3[nt]);   // h2(i-1)@W_hh2
            }
        }

        // Epilogue: h2(i) and h1(i+1)
#pragma unroll
        for (int nt = 0; nt < 2; ++nt)
#pragma unroll
            for (int r = 0; r < 4; ++r) {
                const int row = rowb + r, col = colb + nt * 16;
                float h2v = tanh_fast(acc2[nt][r] + acc3[nt][r] + b2v[nt]);
                hs2[nxt][row * LSTR + col] = (f16)h2v;
                xu[basew + (size_t)row * HH + col] = h2v;       // final output
                if (i == TT - 1) h2f[(size_t)(m0 + row) * HH + col] = h2v;

                float h1v = tanh_fast(acc1[nt][r] + xn[nt][r] + b1v[nt]);
                hs1[nxt][row * LSTR + col] = (f16)h1v;
                if (i == TT - 2) h1f[(size_t)(m0 + row) * HH + col] = h1v;
            }
        lds_barrier();
    }
}

extern "C" void kernel_launch(void* const* d_in, const int* in_sizes, int n_in,
                              void* d_out, int out_size, void* d_ws, size_t ws_size,
                              hipStream_t stream)
{
    const float* A     = (const float*)d_in[0];   // [T,B,X]
    const float* is1   = (const float*)d_in[1];   // [B,H1]
    const float* is2   = (const float*)d_in[2];   // [B,H2]
    const float* W_ih1 = (const float*)d_in[3];
    const float* W_hh1 = (const float*)d_in[4];
    const float* b_ih1 = (const float*)d_in[5];
    const float* b_hh1 = (const float*)d_in[6];
    const float* W_ih2 = (const float*)d_in[7];
    const float* W_hh2 = (const float*)d_in[8];
    const float* b_ih2 = (const float*)d_in[9];
    const float* b_hh2 = (const float*)d_in[10];

    float* out = (float*)d_out;
    const size_t OUT0 = (size_t)TT * BB * HH;          // 33554432
    float* x1  = out;                                  // fp32 scratch in out region
    float* h1f = out + OUT0;
    float* h2f = out + OUT0 + (size_t)BB * HH;
    (void)d_ws; (void)ws_size;                         // unused

    // K1: x1 = A @ W_ih1^T + b_ih1  (single-f16 W, 1 pass)
    proj_kernel<<<dim3(512), dim3(512), 0, stream>>>(A, W_ih1, b_ih1, x1);
    // K2: fused scan (layer1 + u-projection + layer2), in place over x1 -> out
    fused_scan_kernel<<<dim3(16), dim3(512), 0, stream>>>(
        x1, W_hh1, b_hh1, W_ih2, W_hh2, b_ih2, b_hh2, is1, is2, h1f, h2f);
}

// Round 6
// 1037.712 us; speedup vs baseline: 2.2940x; 1.0308x over previous
//
#include <hip/hip_runtime.h>

// UniRNN: T=512,B=256,X=H1=H2=256, fp32 in/out.
// R6 = R5 + bank-conflict-free LDS row permutation (sigma).
//   K1: x1 = A @ W_ih1^T + b_ih1   (single-f16 W, fp32 out)
//   K2: fused scan, merged phase (one barrier/step):
//         h2(i)   = tanh(h1(i)@W_ih2 + h2(i-1)@W_hh2 + b2)
//         h1(i+1) = tanh(h1(i)@W_hh1 + x(i+1) + b1)
// R5 counters: 512 conflict-cyc/WG/step, all write-side: row-stride
// 4*LSTR = 560 dw = 16 mod 32 -> quad0/2 and quad1/3 collide 4-way on the
// 16 ds_write_b16/thread. Fix: store row at sigma(row) so each write instr's
// 4 quads hit disjoint 8-bank windows {0,8,16,24}, while reads stay uniform
// 2-way (free). sigma = [0,8,1,9,6,14,7,15,4,12,5,13,2,10,3,11]; both sides
// of the LDS round-trip apply it -> numerics bit-identical to R5.

#define TT 512
#define BB 256
#define HH 256
#define LSTR 280   // LDS row stride (f16); 140 dw = 12 mod 32 -> reads 2-way-free

typedef _Float16 f16;
typedef _Float16 f16x8 __attribute__((ext_vector_type(8)));
typedef float f32x4  __attribute__((ext_vector_type(4)));

__device__ inline float tanh_fast(float x) {
    float e = __expf(2.0f * x);
    return 1.0f - 2.0f * __builtin_amdgcn_rcpf(e + 1.0f);
}
// LDS-visibility-only barrier: waits DS ops, does NOT drain vmcnt.
__device__ inline void lds_barrier() {
    asm volatile("s_waitcnt lgkmcnt(0)\n\ts_barrier" ::: "memory");
}
// Storage-row permutation: bank-decorrelates quad-strided writes.
// sigma(q*4+r) = ((-2q)&6) | ((r&1)<<3) | (r>>1)
__device__ inline int sigma_row(int row) {
    int q = row >> 2, r = row & 3;
    return ((-(q << 1)) & 6) | ((r & 1) << 3) | (r >> 1);
}
// 8 consecutive fp32 -> single f16x8 fragment (RNE)
__device__ inline f16x8 pack_wfragh(const float* __restrict__ wrow) {
    const float4* p = (const float4*)wrow;
    float4 v0 = p[0], v1 = p[1];
    f16x8 h;
    h[0] = (f16)v0.x; h[1] = (f16)v0.y; h[2] = (f16)v0.z; h[3] = (f16)v0.w;
    h[4] = (f16)v1.x; h[5] = (f16)v1.y; h[6] = (f16)v1.z; h[7] = (f16)v1.w;
    return h;
}
__device__ inline f32x4 mfma16h(f16x8 a, f16x8 b, f32x4 c) {
    return __builtin_amdgcn_mfma_f32_16x16x32_f16(a, b, c, 0, 0, 0);
}

// ---------------------------------------------------------------------------
// K1 projection: x1[m,n] = sum_k A[m,k]*W_ih1[n,k] + b_ih1[n], fp32 out.
// M = T*B = 131072, N = K = 256. 512 thr (8 waves), wave owns 32 cols.
// Tile 64(M) x 256(N); each WG does 4 tiles -> grid 512. Single-f16 W, 1 pass.
// (Writes here are row-contiguous per wave -> already conflict-free; no sigma.)
// ---------------------------------------------------------------------------
__global__ __launch_bounds__(512, 2)
void proj_kernel(const float* __restrict__ Ain, const float* __restrict__ W,
                 const float* __restrict__ bias, float* __restrict__ Cout)
{
    __shared__ f16 lds_a[64 * LSTR];
    const int tid  = threadIdx.x;
    const int lane = tid & 63, wv = tid >> 6;
    const int quad = lane >> 4, l15 = lane & 15;
    const int n0   = wv * 32;

    f16x8 wh[2][8];
    float biasv[2];
#pragma unroll
    for (int nt = 0; nt < 2; ++nt) {
        int n = n0 + nt * 16 + l15;
        biasv[nt] = bias[n];
#pragma unroll
        for (int kc = 0; kc < 8; ++kc)
            wh[nt][kc] = pack_wfragh(W + (size_t)n * HH + kc * 32 + quad * 8);
    }

    for (int it = 0; it < 4; ++it) {
        const int m0 = (blockIdx.x * 4 + it) * 64;
#pragma unroll
        for (int j = 0; j < 8; ++j) {
            int c = tid + j * 512;            // 4096 chunks of 4 fp32
            int row = c >> 6, col4 = c & 63;
            float4 v = *(const float4*)(Ain + (size_t)(m0 + row) * HH + col4 * 4);
            f16 h0 = (f16)v.x, h1 = (f16)v.y, h2 = (f16)v.z, h3 = (f16)v.w;
            unsigned int p0 = (unsigned int)__builtin_bit_cast(unsigned short, h0) |
                              ((unsigned int)__builtin_bit_cast(unsigned short, h1) << 16);
            unsigned int p1 = (unsigned int)__builtin_bit_cast(unsigned short, h2) |
                              ((unsigned int)__builtin_bit_cast(unsigned short, h3) << 16);
            *(uint2*)&lds_a[row * LSTR + col4 * 4] = make_uint2(p0, p1);
        }
        __syncthreads();

        f32x4 acc[4][2];
#pragma unroll
        for (int mt = 0; mt < 4; ++mt)
#pragma unroll
            for (int nt = 0; nt < 2; ++nt)
                acc[mt][nt] = (f32x4){0.f, 0.f, 0.f, 0.f};

#pragma unroll
        for (int kc = 0; kc < 8; ++kc) {
            f16x8 ah[4];
#pragma unroll
            for (int mt = 0; mt < 4; ++mt)
                ah[mt] = *(const f16x8*)&lds_a[(mt * 16 + l15) * LSTR + kc * 32 + quad * 8];
#pragma unroll
            for (int mt = 0; mt < 4; ++mt)
#pragma unroll
                for (int nt = 0; nt < 2; ++nt)
                    acc[mt][nt] = mfma16h(ah[mt], wh[nt][kc], acc[mt][nt]);
        }

#pragma unroll
        for (int mt = 0; mt < 4; ++mt)
#pragma unroll
            for (int nt = 0; nt < 2; ++nt)
#pragma unroll
                for (int r = 0; r < 4; ++r) {
                    int row = m0 + mt * 16 + quad * 4 + r;
                    int col = n0 + nt * 16 + l15;
                    Cout[(size_t)row * HH + col] = acc[mt][nt][r] + biasv[nt];
                }
        __syncthreads();
    }
}

// ---------------------------------------------------------------------------
// Fused scan, merged phase + sigma rows: 16 WGs x 512 thr (8 waves, 2/SIMD).
// WG owns batch rows [m0,m0+16), wave owns 32 cols (2 nt). States h1,h2 fp16
// in LDS (double-buffered, sigma-permuted rows). W_hh1/W_ih2/W_hh2 fp16 regs.
// ---------------------------------------------------------------------------
__global__ __launch_bounds__(512, 2)
void fused_scan_kernel(float* __restrict__ xu,            // [T,B,H] fp32: in x1, out h2
                       const float* __restrict__ Whh1,
                       const float* __restrict__ bhh1,
                       const float* __restrict__ Wih2,
                       const float* __restrict__ Whh2,
                       const float* __restrict__ bih2,
                       const float* __restrict__ bhh2,
                       const float* __restrict__ h10,     // [B,H] fp32
                       const float* __restrict__ h20,     // [B,H] fp32
                       float* __restrict__ h1f,           // [B,H] fp32 final
                       float* __restrict__ h2f)           // [B,H] fp32 final
{
    __shared__ f16 hs1[2][16 * LSTR];
    __shared__ f16 hs2[2][16 * LSTR];
    const int tid  = threadIdx.x;
    const int lane = tid & 63, wv = tid >> 6;
    const int quad = lane >> 4, l15 = lane & 15;
    const int m0   = blockIdx.x * 16;
    const int n0   = wv * 32;

    f16x8 w1[2][8], w2[2][8], w3[2][8];
    float b1v[2], b2v[2];
#pragma unroll
    for (int nt = 0; nt < 2; ++nt) {
        int n = n0 + nt * 16 + l15;
        b1v[nt] = bhh1[n];
        b2v[nt] = bih2[n] + bhh2[n];
#pragma unroll
        for (int kc = 0; kc < 8; ++kc) {
            w1[nt][kc] = pack_wfragh(Whh1 + (size_t)n * HH + kc * 32 + quad * 8);
            w2[nt][kc] = pack_wfragh(Wih2 + (size_t)n * HH + kc * 32 + quad * 8);
            w3[nt][kc] = pack_wfragh(Whh2 + (size_t)n * HH + kc * 32 + quad * 8);
        }
    }

    // Per-lane precomputed storage rows.
    const int srd = sigma_row(l15);                 // read row for this lane
    int swr[4];                                     // write rows (r=0..3)
#pragma unroll
    for (int r = 0; r < 4; ++r) swr[r] = sigma_row(quad * 4 + r);

    // init: is1 -> hs1[1] (consumed by prologue GEMM), is2 -> hs2[0].
#pragma unroll
    for (int j = 0; j < 8; ++j) {
        int idx = tid + j * 512;
        int row = idx >> 8, col = idx & 255;
        int sr = sigma_row(row);
        hs1[1][sr * LSTR + col] = (f16)h10[(size_t)(m0 + row) * HH + col];
        hs2[0][sr * LSTR + col] = (f16)h20[(size_t)(m0 + row) * HH + col];
    }
    __syncthreads();

    const int colb = n0 + l15;
    const int rowb = quad * 4;

    // Prologue: h1(0) = tanh(x(0) + is1@W_hh1 + b1) -> hs1[0]
    {
        float x0[2][4];
#pragma unroll
        for (int nt = 0; nt < 2; ++nt)
#pragma unroll
            for (int r = 0; r < 4; ++r)
                x0[nt][r] = xu[(size_t)(m0 + rowb + r) * HH + colb + nt * 16];

        f32x4 p[2] = {(f32x4){0.f,0.f,0.f,0.f}, (f32x4){0.f,0.f,0.f,0.f}};
#pragma unroll
        for (int kc = 0; kc < 8; ++kc) {
            f16x8 a = *(const f16x8*)&hs1[1][srd * LSTR + kc * 32 + quad * 8];
#pragma unroll
            for (int nt = 0; nt < 2; ++nt)
                p[nt] = mfma16h(a, w1[nt][kc], p[nt]);
        }
#pragma unroll
        for (int nt = 0; nt < 2; ++nt)
#pragma unroll
            for (int r = 0; r < 4; ++r) {
                float h = tanh_fast(p[nt][r] + x0[nt][r] + b1v[nt]);
                hs1[0][swr[r] * LSTR + colb + nt * 16] = (f16)h;
            }
        __syncthreads();
    }

    // Main loop: phase i computes h2(i) and h1(i+1), one barrier.
    for (int i = 0; i < TT; ++i) {
        const int cur = i & 1, nxt = cur ^ 1;
        const size_t basew = ((size_t)i * BB + m0) * HH;               // h2(i) out
        const int ir = (i + 1 < TT) ? (i + 1) : i;                     // clamp
        const size_t baser = ((size_t)ir * BB + m0) * HH;              // x(i+1) in

        // x(i+1): issued early; MFMAs + ds_reads cover the HBM latency.
        float xn[2][4];
#pragma unroll
        for (int nt = 0; nt < 2; ++nt)
#pragma unroll
            for (int r = 0; r < 4; ++r)
                xn[nt][r] = xu[baser + (size_t)(rowb + r) * HH + colb + nt * 16];

        f32x4 acc1[2] = {(f32x4){0.f,0.f,0.f,0.f}, (f32x4){0.f,0.f,0.f,0.f}};
        f32x4 acc2[2] = {(f32x4){0.f,0.f,0.f,0.f}, (f32x4){0.f,0.f,0.f,0.f}};
        f32x4 acc3[2] = {(f32x4){0.f,0.f,0.f,0.f}, (f32x4){0.f,0.f,0.f,0.f}};
#pragma unroll
        for (int kc = 0; kc < 8; ++kc) {
            f16x8 a1 = *(const f16x8*)&hs1[cur][srd * LSTR + kc * 32 + quad * 8];
            f16x8 a2 = *(const f16x8*)&hs2[cur][srd * LSTR + kc * 32 + quad * 8];
#pragma unroll
            for (int nt = 0; nt < 2; ++nt) {
                acc2[nt] = mfma16h(a1, w2[nt][kc], acc2[nt]);   // u(i)   = h1(i)@W_ih2
                acc1[nt] = mfma16h(a1, w1[nt][kc], acc1[nt]);   // pre-h1(i+1)
                acc3[nt] = mfma16h(a2, w3[nt][kc], acc3[nt]);   // h2(i-1)@W_hh2
            }
        }

        // Epilogue: h2(i) and h1(i+1)
#pragma unroll
        for (int nt = 0; nt < 2; ++nt)
#pragma unroll
            for (int r = 0; r < 4; ++r) {
                const int row = rowb + r, col = colb + nt * 16;
                float h2v = tanh_fast(acc2[nt][r] + acc3[nt][r] + b2v[nt]);
                hs2[nxt][swr[r] * LSTR + col] = (f16)h2v;
                xu[basew + (size_t)row * HH + col] = h2v;       // final output
                if (i == TT - 1) h2f[(size_t)(m0 + row) * HH + col] = h2v;

                float h1v = tanh_fast(acc1[nt][r] + xn[nt][r] + b1v[nt]);
                hs1[nxt][swr[r] * LSTR + col] = (f16)h1v;
                if (i == TT - 2) h1f[(size_t)(m0 + row) * HH + col] = h1v;
            }
        lds_barrier();
    }
}

extern "C" void kernel_launch(void* const* d_in, const int* in_sizes, int n_in,
                              void* d_out, int out_size, void* d_ws, size_t ws_size,
                              hipStream_t stream)
{
    const float* A     = (const float*)d_in[0];   // [T,B,X]
    const float* is1   = (const float*)d_in[1];   // [B,H1]
    const float* is2   = (const float*)d_in[2];   // [B,H2]
    const float* W_ih1 = (const float*)d_in[3];
    const float* W_hh1 = (const float*)d_in[4];
    const float* b_ih1 = (const float*)d_in[5];
    const float* b_hh1 = (const float*)d_in[6];
    const float* W_ih2 = (const float*)d_in[7];
    const float* W_hh2 = (const float*)d_in[8];
    const float* b_ih2 = (const float*)d_in[9];
    const float* b_hh2 = (const float*)d_in[10];

    float* out = (float*)d_out;
    const size_t OUT0 = (size_t)TT * BB * HH;          // 33554432
    float* x1  = out;                                  // fp32 scratch in out region
    float* h1f = out + OUT0;
    float* h2f = out + OUT0 + (size_t)BB * HH;
    (void)d_ws; (void)ws_size;                         // unused

    // K1: x1 = A @ W_ih1^T + b_ih1  (single-f16 W, 1 pass)
    proj_kernel<<<dim3(512), dim3(512), 0, stream>>>(A, W_ih1, b_ih1, x1);
    // K2: fused scan (layer1 + u-projection + layer2), in place over x1 -> out
    fused_scan_kernel<<<dim3(16), dim3(512), 0, stream>>>(
        x1, W_hh1, b_hh1, W_ih2, W_hh2, b_ih2, b_hh2, is1, is2, h1f, h2f);
}

// Round 8
// 1033.463 us; speedup vs baseline: 2.3035x; 1.0041x over previous
//
#include <hip/hip_runtime.h>

// UniRNN: T=512,B=256,X=H1=H2=256, fp32 in/out.
// R8 = R6 + software-pipelined K1, CORRECTED (R7 staged only 1/4 tile -> NaN).
//   K1: x1 = A @ W_ih1^T + b_ih1   (single-f16 W, fp32 out)
//       Full-tile register prefetch: float4 pa[8] = 32 f32/thread (R6's exact
//       coalesced addressing), staged to LDS at iter top; next tile's loads
//       issued right after the publish barrier so 64 MFMA + 32 stores cover
//       the ~900cy HBM latency (T14 issue-early/consume-late).
//   K2: fused scan UNCHANGED from R6 (793us measured; LDS/VALU/MFMA balanced;
//       4.2M conflicts are read-structural (b128 shape), sigma fixes writes).

#define TT 512
#define BB 256
#define HH 256
#define LSTR 280   // LDS row stride (f16); 140 dw = 12 mod 32 -> reads 2-way-free

typedef _Float16 f16;
typedef _Float16 f16x8 __attribute__((ext_vector_type(8)));
typedef float f32x4  __attribute__((ext_vector_type(4)));

__device__ inline float tanh_fast(float x) {
    float e = __expf(2.0f * x);
    return 1.0f - 2.0f * __builtin_amdgcn_rcpf(e + 1.0f);
}
// LDS-visibility-only barrier: waits DS ops, does NOT drain vmcnt.
__device__ inline void lds_barrier() {
    asm volatile("s_waitcnt lgkmcnt(0)\n\ts_barrier" ::: "memory");
}
// Storage-row permutation: bank-decorrelates quad-strided writes.
__device__ inline int sigma_row(int row) {
    int q = row >> 2, r = row & 3;
    return ((-(q << 1)) & 6) | ((r & 1) << 3) | (r >> 1);
}
// 8 consecutive fp32 -> single f16x8 fragment (RNE)
__device__ inline f16x8 pack_wfragh(const float* __restrict__ wrow) {
    const float4* p = (const float4*)wrow;
    float4 v0 = p[0], v1 = p[1];
    f16x8 h;
    h[0] = (f16)v0.x; h[1] = (f16)v0.y; h[2] = (f16)v0.z; h[3] = (f16)v0.w;
    h[4] = (f16)v1.x; h[5] = (f16)v1.y; h[6] = (f16)v1.z; h[7] = (f16)v1.w;
    return h;
}
__device__ inline f32x4 mfma16h(f16x8 a, f16x8 b, f32x4 c) {
    return __builtin_amdgcn_mfma_f32_16x16x32_f16(a, b, c, 0, 0, 0);
}

// ---------------------------------------------------------------------------
// K1 projection, software-pipelined: x1[m,n] = sum_k A[m,k]*W_ih1[n,k] + b[n].
// M = T*B = 131072, N = K = 256. 512 thr (8 waves), wave owns 32 cols.
// Tile 64(M) x 256(N); 4 tiles/WG -> grid 512. Single-f16 W, 1 pass.
// Pipeline: float4 pa[8] (full 64x256 tile across 512 threads) holds tile
// it+1's A while LDS holds tile it.
// ---------------------------------------------------------------------------
__global__ __launch_bounds__(512, 2)
void proj_kernel(const float* __restrict__ Ain, const float* __restrict__ W,
                 const float* __restrict__ bias, float* __restrict__ Cout)
{
    __shared__ f16 lds_a[64 * LSTR];
    const int tid  = threadIdx.x;
    const int lane = tid & 63, wv = tid >> 6;
    const int quad = lane >> 4, l15 = lane & 15;
    const int n0   = wv * 32;

    f16x8 wh[2][8];
    float biasv[2];
#pragma unroll
    for (int nt = 0; nt < 2; ++nt) {
        int n = n0 + nt * 16 + l15;
        biasv[nt] = bias[n];
#pragma unroll
        for (int kc = 0; kc < 8; ++kc)
            wh[nt][kc] = pack_wfragh(W + (size_t)n * HH + kc * 32 + quad * 8);
    }

    const int m00 = blockIdx.x * 4 * 64;

    // prologue: load tile 0 fully into regs (32 f32/thread, coalesced)
    float4 pa[8];
#pragma unroll
    for (int j = 0; j < 8; ++j) {
        int c = tid + j * 512;                 // 4096 chunks of 4 fp32
        int row = c >> 6, col4 = c & 63;
        pa[j] = *(const float4*)(Ain + (size_t)(m00 + row) * HH + col4 * 4);
    }

    for (int it = 0; it < 4; ++it) {
        const int m0 = m00 + it * 64;

        // stage regs -> LDS (cvt fp32->f16), same addressing as the loads
#pragma unroll
        for (int j = 0; j < 8; ++j) {
            int c = tid + j * 512;
            int row = c >> 6, col4 = c & 63;
            float4 v = pa[j];
            f16 h0 = (f16)v.x, h1 = (f16)v.y, h2 = (f16)v.z, h3 = (f16)v.w;
            unsigned int p0 = (unsigned int)__builtin_bit_cast(unsigned short, h0) |
                              ((unsigned int)__builtin_bit_cast(unsigned short, h1) << 16);
            unsigned int p1 = (unsigned int)__builtin_bit_cast(unsigned short, h2) |
                              ((unsigned int)__builtin_bit_cast(unsigned short, h3) << 16);
            *(uint2*)&lds_a[row * LSTR + col4 * 4] = make_uint2(p0, p1);
        }
        __syncthreads();

        // issue next tile's loads NOW; MFMA + stores below cover the latency
        if (it < 3) {
#pragma unroll
            for (int j = 0; j < 8; ++j) {
                int c = tid + j * 512;
                int row = c >> 6, col4 = c & 63;
                pa[j] = *(const float4*)(Ain + (size_t)(m0 + 64 + row) * HH + col4 * 4);
            }
        }

        f32x4 acc[4][2];
#pragma unroll
        for (int mt = 0; mt < 4; ++mt)
#pragma unroll
            for (int nt = 0; nt < 2; ++nt)
                acc[mt][nt] = (f32x4){0.f, 0.f, 0.f, 0.f};

#pragma unroll
        for (int kc = 0; kc < 8; ++kc) {
            f16x8 ah[4];
#pragma unroll
            for (int mt = 0; mt < 4; ++mt)
                ah[mt] = *(const f16x8*)&lds_a[(mt * 16 + l15) * LSTR + kc * 32 + quad * 8];
#pragma unroll
            for (int mt = 0; mt < 4; ++mt)
#pragma unroll
                for (int nt = 0; nt < 2; ++nt)
                    acc[mt][nt] = mfma16h(ah[mt], wh[nt][kc], acc[mt][nt]);
        }

#pragma unroll
        for (int mt = 0; mt < 4; ++mt)
#pragma unroll
            for (int nt = 0; nt < 2; ++nt)
#pragma unroll
                for (int r = 0; r < 4; ++r) {
                    int row = m0 + mt * 16 + quad * 4 + r;
                    int col = n0 + nt * 16 + l15;
                    Cout[(size_t)row * HH + col] = acc[mt][nt][r] + biasv[nt];
                }
        __syncthreads();   // protect LDS before next stage
    }
}

// ---------------------------------------------------------------------------
// Fused scan, merged phase + sigma rows: 16 WGs x 512 thr (8 waves, 2/SIMD).
// WG owns batch rows [m0,m0+16), wave owns 32 cols (2 nt). States h1,h2 fp16
// in LDS (double-buffered, sigma-permuted rows). W_hh1/W_ih2/W_hh2 fp16 regs.
// Phase i: h2(i) = tanh(h1(i)@W_ih2 + h2(i-1)@W_hh2 + b2);
//          h1(i+1) = tanh(h1(i)@W_hh1 + x(i+1) + b1). One barrier/step.
// ---------------------------------------------------------------------------
__global__ __launch_bounds__(512, 2)
void fused_scan_kernel(float* __restrict__ xu,            // [T,B,H] fp32: in x1, out h2
                       const float* __restrict__ Whh1,
                       const float* __restrict__ bhh1,
                       const float* __restrict__ Wih2,
                       const float* __restrict__ Whh2,
                       const float* __restrict__ bih2,
                       const float* __restrict__ bhh2,
                       const float* __restrict__ h10,     // [B,H] fp32
                       const float* __restrict__ h20,     // [B,H] fp32
                       float* __restrict__ h1f,           // [B,H] fp32 final
                       float* __restrict__ h2f)           // [B,H] fp32 final
{
    __shared__ f16 hs1[2][16 * LSTR];
    __shared__ f16 hs2[2][16 * LSTR];
    const int tid  = threadIdx.x;
    const int lane = tid & 63, wv = tid >> 6;
    const int quad = lane >> 4, l15 = lane & 15;
    const int m0   = blockIdx.x * 16;
    const int n0   = wv * 32;

    f16x8 w1[2][8], w2[2][8], w3[2][8];
    float b1v[2], b2v[2];
#pragma unroll
    for (int nt = 0; nt < 2; ++nt) {
        int n = n0 + nt * 16 + l15;
        b1v[nt] = bhh1[n];
        b2v[nt] = bih2[n] + bhh2[n];
#pragma unroll
        for (int kc = 0; kc < 8; ++kc) {
            w1[nt][kc] = pack_wfragh(Whh1 + (size_t)n * HH + kc * 32 + quad * 8);
            w2[nt][kc] = pack_wfragh(Wih2 + (size_t)n * HH + kc * 32 + quad * 8);
            w3[nt][kc] = pack_wfragh(Whh2 + (size_t)n * HH + kc * 32 + quad * 8);
        }
    }

    // Per-lane precomputed storage rows.
    const int srd = sigma_row(l15);                 // read row for this lane
    int swr[4];                                     // write rows (r=0..3)
#pragma unroll
    for (int r = 0; r < 4; ++r) swr[r] = sigma_row(quad * 4 + r);

    // init: is1 -> hs1[1] (consumed by prologue GEMM), is2 -> hs2[0].
#pragma unroll
    for (int j = 0; j < 8; ++j) {
        int idx = tid + j * 512;
        int row = idx >> 8, col = idx & 255;
        int sr = sigma_row(row);
        hs1[1][sr * LSTR + col] = (f16)h10[(size_t)(m0 + row) * HH + col];
        hs2[0][sr * LSTR + col] = (f16)h20[(size_t)(m0 + row) * HH + col];
    }
    __syncthreads();

    const int colb = n0 + l15;
    const int rowb = quad * 4;

    // Prologue: h1(0) = tanh(x(0) + is1@W_hh1 + b1) -> hs1[0]
    {
        float x0[2][4];
#pragma unroll
        for (int nt = 0; nt < 2; ++nt)
#pragma unroll
            for (int r = 0; r < 4; ++r)
                x0[nt][r] = xu[(size_t)(m0 + rowb + r) * HH + colb + nt * 16];

        f32x4 p[2] = {(f32x4){0.f,0.f,0.f,0.f}, (f32x4){0.f,0.f,0.f,0.f}};
#pragma unroll
        for (int kc = 0; kc < 8; ++kc) {
            f16x8 a = *(const f16x8*)&hs1[1][srd * LSTR + kc * 32 + quad * 8];
#pragma unroll
            for (int nt = 0; nt < 2; ++nt)
                p[nt] = mfma16h(a, w1[nt][kc], p[nt]);
        }
#pragma unroll
        for (int nt = 0; nt < 2; ++nt)
#pragma unroll
            for (int r = 0; r < 4; ++r) {
                float h = tanh_fast(p[nt][r] + x0[nt][r] + b1v[nt]);
                hs1[0][swr[r] * LSTR + colb + nt * 16] = (f16)h;
            }
        __syncthreads();
    }

    // Main loop: phase i computes h2(i) and h1(i+1), one barrier.
    for (int i = 0; i < TT; ++i) {
        const int cur = i & 1, nxt = cur ^ 1;
        const size_t basew = ((size_t)i * BB + m0) * HH;               // h2(i) out
        const int ir = (i + 1 < TT) ? (i + 1) : i;                     // clamp
        const size_t baser = ((size_t)ir * BB + m0) * HH;              // x(i+1) in

        // x(i+1): issued early; MFMAs + ds_reads cover the HBM latency.
        float xn[2][4];
#pragma unroll
        for (int nt = 0; nt < 2; ++nt)
#pragma unroll
            for (int r = 0; r < 4; ++r)
                xn[nt][r] = xu[baser + (size_t)(rowb + r) * HH + colb + nt * 16];

        f32x4 acc1[2] = {(f32x4){0.f,0.f,0.f,0.f}, (f32x4){0.f,0.f,0.f,0.f}};
        f32x4 acc2[2] = {(f32x4){0.f,0.f,0.f,0.f}, (f32x4){0.f,0.f,0.f,0.f}};
        f32x4 acc3[2] = {(f32x4){0.f,0.f,0.f,0.f}, (f32x4){0.f,0.f,0.f,0.f}};
#pragma unroll
        for (int kc = 0; kc < 8; ++kc) {
            f16x8 a1 = *(const f16x8*)&hs1[cur][srd * LSTR + kc * 32 + quad * 8];
            f16x8 a2 = *(const f16x8*)&hs2[cur][srd * LSTR + kc * 32 + quad * 8];
#pragma unroll
            for (int nt = 0; nt < 2; ++nt) {
                acc2[nt] = mfma16h(a1, w2[nt][kc], acc2[nt]);   // u(i)   = h1(i)@W_ih2
                acc1[nt] = mfma16h(a1, w1[nt][kc], acc1[nt]);   // pre-h1(i+1)
                acc3[nt] = mfma16h(a2, w3[nt][kc], acc3[nt]);   // h2(i-1)@W_hh2
            }
        }

        // Epilogue: h2(i) and h1(i+1)
#pragma unroll
        for (int nt = 0; nt < 2; ++nt)
#pragma unroll
            for (int r = 0; r < 4; ++r) {
                const int row = rowb + r, col = colb + nt * 16;
                float h2v = tanh_fast(acc2[nt][r] + acc3[nt][r] + b2v[nt]);
                hs2[nxt][swr[r] * LSTR + col] = (f16)h2v;
                xu[basew + (size_t)row * HH + col] = h2v;       // final output
                if (i == TT - 1) h2f[(size_t)(m0 + row) * HH + col] = h2v;

                float h1v = tanh_fast(acc1[nt][r] + xn[nt][r] + b1v[nt]);
                hs1[nxt][swr[r] * LSTR + col] = (f16)h1v;
                if (i == TT - 2) h1f[(size_t)(m0 + row) * HH + col] = h1v;
            }
        lds_barrier();
    }
}

extern "C" void kernel_launch(void* const* d_in, const int* in_sizes, int n_in,
                              void* d_out, int out_size, void* d_ws, size_t ws_size,
                              hipStream_t stream)
{
    const float* A     = (const float*)d_in[0];   // [T,B,X]
    const float* is1   = (const float*)d_in[1];   // [B,H1]
    const float* is2   = (const float*)d_in[2];   // [B,H2]
    const float* W_ih1 = (const float*)d_in[3];
    const float* W_hh1 = (const float*)d_in[4];
    const float* b_ih1 = (const float*)d_in[5];
    const float* b_hh1 = (const float*)d_in[6];
    const float* W_ih2 = (const float*)d_in[7];
    const float* W_hh2 = (const float*)d_in[8];
    const float* b_ih2 = (const float*)d_in[9];
    const float* b_hh2 = (const float*)d_in[10];

    float* out = (float*)d_out;
    const size_t OUT0 = (size_t)TT * BB * HH;          // 33554432
    float* x1  = out;                                  // fp32 scratch in out region
    float* h1f = out + OUT0;
    float* h2f = out + OUT0 + (size_t)BB * HH;
    (void)d_ws; (void)ws_size;                         // unused

    // K1: x1 = A @ W_ih1^T + b_ih1  (single-f16 W, 1 pass, pipelined tiles)
    proj_kernel<<<dim3(512), dim3(512), 0, stream>>>(A, W_ih1, b_ih1, x1);
    // K2: fused scan (layer1 + u-projection + layer2), in place over x1 -> out
    fused_scan_kernel<<<dim3(16), dim3(512), 0, stream>>>(
        x1, W_hh1, b_hh1, W_ih2, W_hh2, b_ih2, b_hh2, is1, is2, h1f, h2f);
}